// Round 10
// baseline (2353.639 us; speedup 1.0000x reference)
//
#include <hip/hip_runtime.h>

#define NL   8
#define DIM  2048
#define NH   8
#define NKV  2
#define HD   256
#define KVL  4096
#define FFI  8192
#define PLD  256
#define POS  2047
#define NCH  64
#define CP   32

__device__ __forceinline__ float dot4(float4 a, float4 b){
  return a.x*b.x + a.y*b.y + a.z*b.z + a.w*b.w;
}

__device__ __forceinline__ float waveAllSum(float v){
#pragma unroll
  for(int o=1;o<64;o<<=1) v += __shfl_xor(v,o,64);
  return v;
}

__device__ __forceinline__ float blockSum256(float v, float* red){
  int lane = threadIdx.x & 63, w = threadIdx.x >> 6;
  v = waveAllSum(v);
  __syncthreads();
  if(lane==0) red[w] = v;
  __syncthreads();
  return red[0]+red[1]+red[2]+red[3];
}

__device__ __forceinline__ float gelu_tanh(float v){
  return 0.5f*v*(1.0f + tanhf(0.7978845608028654f*(v + 0.044715f*v*v*v)));
}

__device__ __forceinline__ float4 normRope(const float* __restrict__ raw, int lane,
    const float* __restrict__ gain, const float* __restrict__ cosT,
    const float* __restrict__ sinT, bool doRope){
  float4 v4 = ((const float4*)raw)[lane];
  float ss = waveAllSum(dot4(v4,v4));
  float sc = rsqrtf(ss*(1.f/HD) + 1e-6f);
  float4 n;
  if(gain){
    float4 g4 = ((const float4*)gain)[lane];
    n.x=v4.x*sc*g4.x; n.y=v4.y*sc*g4.y; n.z=v4.z*sc*g4.z; n.w=v4.w*sc*g4.w;
  } else {
    n.x=v4.x*sc; n.y=v4.y*sc; n.z=v4.z*sc; n.w=v4.w*sc;
  }
  if(!doRope) return n;
  float4 np;
  np.x=__shfl_xor(n.x,32,64); np.y=__shfl_xor(n.y,32,64);
  np.z=__shfl_xor(n.z,32,64); np.w=__shfl_xor(n.w,32,64);
  float4 c4 = ((const float4*)cosT)[lane];
  float4 s4 = ((const float4*)sinT)[lane];
  float sg = (lane < 32) ? -1.f : 1.f;
  float4 o;
  o.x = n.x*c4.x + sg*np.x*s4.x;
  o.y = n.y*c4.y + sg*np.y*s4.y;
  o.z = n.z*c4.z + sg*np.z*s4.z;
  o.w = n.w*c4.w + sg*np.w*s4.w;
  return o;
}

// ---- qkv GEMV with fused post_pl (prev layer) / initial prologue ----
__global__ __launch_bounds__(256) void qkv_k(
    const float* __restrict__ Wq, const float* __restrict__ Wk,
    const float* __restrict__ Wv,
    const float* __restrict__ hFF, const float* __restrict__ u,
    const float* __restrict__ g_pl, const float* __restrict__ lsc,
    const float* __restrict__ g_in, const float* __restrict__ hidden,
    float* __restrict__ hRes, float* __restrict__ qkv){
  __shared__ float xs[DIM];
  __shared__ float red[4];
  int tid = threadIdx.x;
  float hv[8];
  if(hidden){
#pragma unroll
    for(int i=0;i<8;i++) hv[i] = hidden[tid + i*256];
  } else {
    float uv[8]; float ss1 = 0.f;
#pragma unroll
    for(int i=0;i<8;i++){ uv[i] = u[tid + i*256]; ss1 += uv[i]*uv[i]; }
    ss1 = blockSum256(ss1, red);
    float r1 = rsqrtf(ss1*(1.f/DIM) + 1e-6f);
    float ls = lsc[0];
#pragma unroll
    for(int i=0;i<8;i++){
      int idx = tid + i*256;
      hv[i] = (hFF[idx] + uv[i]*r1*g_pl[idx])*ls;
    }
  }
  float ss2 = 0.f;
#pragma unroll
  for(int i=0;i<8;i++) ss2 += hv[i]*hv[i];
  ss2 = blockSum256(ss2, red);
  float r2 = rsqrtf(ss2*(1.f/DIM) + 1e-6f);
#pragma unroll
  for(int i=0;i<8;i++){
    int idx = tid + i*256;
    xs[idx] = hv[i]*r2*g_in[idx];
    if(blockIdx.x==0) hRes[idx] = hv[i];
  }
  __syncthreads();
  int lane = tid & 63, wv = tid >> 6;
  int r = blockIdx.x*4 + wv;
  const float* W; int row;
  if(r < 2048){ W = Wq; row = r; }
  else if(r < 2560){ W = Wk; row = r - 2048; }
  else { W = Wv; row = r - 2560; }
  const float4* Wr = (const float4*)(W + (size_t)row*DIM);
  const float4* xs4 = (const float4*)xs;
  float4 w8[8];
#pragma unroll
  for(int i=0;i<8;i++) w8[i] = Wr[i*64+lane];
  float acc = 0.f;
#pragma unroll
  for(int i=0;i<8;i++) acc += dot4(w8[i], xs4[i*64+lane]);
  acc = waveAllSum(acc);
  if(lane==0) qkv[r] = acc;
}

// ---- attention: fused q/k/v norm+rope, flash partials; +1 cache-row writer ----
__global__ __launch_bounds__(256) void attn_k(
    const float* __restrict__ qkvb,
    const float* __restrict__ gq, const float* __restrict__ gk,
    const float* __restrict__ cosT, const float* __restrict__ sinT,
    const float* __restrict__ Ki, const float* __restrict__ Vi,
    float* __restrict__ Kl, float* __restrict__ Vl,
    float* __restrict__ pm, float* __restrict__ pl, float* __restrict__ po){
  int b = blockIdx.x, tid = threadIdx.x, lane = tid & 63, wv = tid >> 6;

  if(b == NKV*NCH){ // cache-row writer
    int kvv = wv >> 1, isV = wv & 1;
    const float* raw = qkvb + (isV ? 2560 : 2048) + kvv*HD;
    float4 o = normRope(raw, lane, isV ? nullptr : gk, cosT, sinT, !isV);
    float* dst = (isV ? Vl : Kl) + ((size_t)kvv*KVL + POS)*HD;
    ((float4*)dst)[lane] = o;
    return;
  }

  int kv = b & 1, c = b >> 1;          // c: 0..63
  __shared__ float q_s[4][HD];
  __shared__ float vf_s[HD];
  __shared__ float s_s[4][CP];
  __shared__ float s_w[4][CP];
  bool fresh = (c == NCH-1);

  { float4 o = normRope(qkvb + (kv*4 + wv)*HD, lane, gq, cosT, sinT, true);
    ((float4*)q_s[wv])[lane] = o; }
  float4 kf4 = {0,0,0,0};
  if(fresh){
    if(wv == 3) kf4 = normRope(qkvb + 2048 + kv*HD, lane, gk, cosT, sinT, true);
    if(wv == 1){
      float4 o = normRope(qkvb + 2560 + kv*HD, lane, nullptr, cosT, sinT, false);
      ((float4*)vf_s)[lane] = o;
    }
  }
  __syncthreads();

  float4 q4[4];
#pragma unroll
  for(int hh=0;hh<4;hh++) q4[hh] = ((const float4*)q_s[hh])[lane];
  const float4* Kp = (const float4*)(Ki + ((size_t)kv*KVL + c*CP)*HD);
#pragma unroll
  for(int j=0;j<8;j++){
    int p = wv*8 + j;
    float4 k4 = (fresh && p==CP-1) ? kf4 : Kp[(size_t)p*64 + lane];
    float d0 = dot4(k4,q4[0]), d1 = dot4(k4,q4[1]);
    float d2 = dot4(k4,q4[2]), d3 = dot4(k4,q4[3]);
    d0 = waveAllSum(d0); d1 = waveAllSum(d1);
    d2 = waveAllSum(d2); d3 = waveAllSum(d3);
    if(lane==0){ s_s[0][p]=d0; s_s[1][p]=d1; s_s[2][p]=d2; s_s[3][p]=d3; }
  }
  __syncthreads();

  if(tid < 128){ // head hh = tid>>5, position pp = tid&31 (32-lane groups)
    int hh = tid >> 5, pp = tid & 31;
    float s = s_s[hh][pp];
    float m = s;
#pragma unroll
    for(int o=1;o<32;o<<=1) m = fmaxf(m, __shfl_xor(m,o,64));
    float e = __expf(s - m);
    float ls = e;
#pragma unroll
    for(int o=1;o<32;o<<=1) ls += __shfl_xor(ls,o,64);
    s_w[hh][pp] = e;
    if(pp==0){ int hg = kv*4 + hh; pm[hg*NCH + c] = m; pl[hg*NCH + c] = ls; }
  }
  __syncthreads();

  int d = tid;
  const float* Vp = Vi + ((size_t)kv*KVL + c*CP)*HD;
  float acc[4] = {0.f,0.f,0.f,0.f};
#pragma unroll 8
  for(int p2=0;p2<CP;p2++){
    float vv = (fresh && p2==CP-1) ? vf_s[d] : Vp[(size_t)p2*HD + d];
#pragma unroll
    for(int hh=0;hh<4;hh++) acc[hh] += s_w[hh][p2]*vv;
  }
#pragma unroll
  for(int hh=0;hh<4;hh++)
    po[((size_t)(kv*4+hh)*NCH + c)*HD + d] = acc[hh];
}

// ---- wo GEMV with fused chunk-combine prologue; also zeros mv slice ----
__global__ __launch_bounds__(256) void wo_k(const float* __restrict__ Wo,
    const float* __restrict__ pm, const float* __restrict__ pl,
    const float* __restrict__ po, float* __restrict__ y, float* __restrict__ mv){
  __shared__ float ao_s[DIM];
  __shared__ float se_s[NH][NCH];
  __shared__ float Li[NH];
  int b = blockIdx.x, tid = threadIdx.x, lane = tid & 63, wv = tid >> 6;
  // zero mv slice (2048 floats over 128 blocks = 4 float4 each)
  if(tid < 4){
    float4 z = {0.f,0.f,0.f,0.f};
    ((float4*)mv)[b*4 + tid] = z;
  }
  { // combine weights: 8 heads x 32 threads
    int h = tid >> 5, q2 = tid & 31;
    float m0 = pm[h*NCH + q2], m1 = pm[h*NCH + 32 + q2];
    float l0 = pl[h*NCH + q2], l1 = pl[h*NCH + 32 + q2];
    float m = fmaxf(m0, m1);
#pragma unroll
    for(int o=1;o<32;o<<=1) m = fmaxf(m, __shfl_xor(m,o,64));
    float e0 = __expf(m0-m), e1 = __expf(m1-m);
    se_s[h][q2] = e0; se_s[h][q2+32] = e1;
    float lp = l0*e0 + l1*e1;
#pragma unroll
    for(int o=1;o<32;o<<=1) lp += __shfl_xor(lp,o,64);
    if(q2==0) Li[h] = 1.f/lp;
  }
  __syncthreads();
#pragma unroll 1
  for(int h=0;h<NH;h++){
    float a = 0.f;
#pragma unroll 8
    for(int c=0;c<NCH;c++)
      a += po[((size_t)(h*NCH) + c)*HD + tid]*se_s[h][c];
    ao_s[h*HD + tid] = a*Li[h];
  }
  __syncthreads();
  const float4* xs4 = (const float4*)ao_s;
#pragma unroll
  for(int j=0;j<4;j++){
    int r = b*16 + wv*4 + j;
    const float4* Wr = (const float4*)(Wo + (size_t)r*DIM);
    float4 w8[8];
#pragma unroll
    for(int i=0;i<8;i++) w8[i] = Wr[i*64+lane];
    float acc = 0.f;
#pragma unroll
    for(int i=0;i<8;i++) acc += dot4(w8[i], xs4[i*64+lane]);
    acc = waveAllSum(acc);
    if(lane==0) y[r] = acc;
  }
}

// ---- gate/up GEMV + down split-K atomic, with fused post_attn prologue ----
__global__ __launch_bounds__(256) void gud_k(const float* __restrict__ Wg,
    const float* __restrict__ Wu, const float* __restrict__ Wd,
    const float* __restrict__ y, const float* __restrict__ hRes,
    const float* __restrict__ gpa, const float* __restrict__ gpf,
    float* __restrict__ hMid, float* __restrict__ mv){
  __shared__ float xs[DIM];
  __shared__ float ts[32];
  __shared__ float red[4];
  int tid = threadIdx.x, lane = tid & 63, wv = tid >> 6;
  float yv[8]; float ss1 = 0.f;
#pragma unroll
  for(int i=0;i<8;i++){ yv[i] = y[tid + i*256]; ss1 += yv[i]*yv[i]; }
  ss1 = blockSum256(ss1, red);
  float r1 = rsqrtf(ss1*(1.f/DIM) + 1e-6f);
  float hv[8]; float ss2 = 0.f;
#pragma unroll
  for(int i=0;i<8;i++){
    int idx = tid + i*256;
    hv[i] = hRes[idx] + yv[i]*r1*gpa[idx];
    ss2 += hv[i]*hv[i];
  }
  ss2 = blockSum256(ss2, red);
  float r2 = rsqrtf(ss2*(1.f/DIM) + 1e-6f);
#pragma unroll
  for(int i=0;i<8;i++){
    int idx = tid + i*256;
    xs[idx] = hv[i]*r2*gpf[idx];
    if(blockIdx.x==0) hMid[idx] = hv[i];
  }
  __syncthreads();
  const float4* xs4 = (const float4*)xs;
  int j0 = blockIdx.x*32;
#pragma unroll 1
  for(int jj=0;jj<8;jj++){
    int j = j0 + wv*8 + jj;
    const float4* Gr = (const float4*)(Wg + (size_t)j*DIM);
    const float4* Ur = (const float4*)(Wu + (size_t)j*DIM);
    float4 g8[8], u8[8];
#pragma unroll
    for(int i=0;i<8;i++) g8[i] = Gr[i*64+lane];
#pragma unroll
    for(int i=0;i<8;i++) u8[i] = Ur[i*64+lane];
    float ag = 0.f, au = 0.f;
#pragma unroll
    for(int i=0;i<8;i++){
      float4 bv = xs4[i*64+lane];
      ag += dot4(g8[i], bv);
      au += dot4(u8[i], bv);
    }
    ag = waveAllSum(ag);
    au = waveAllSum(au);
    if(lane==0) ts[wv*8+jj] = gelu_tanh(ag)*au;
  }
  __syncthreads();
  const float4* ts4 = (const float4*)ts;
  float4 t8[8];
#pragma unroll
  for(int i=0;i<8;i++) t8[i] = ts4[i];
#pragma unroll 1
  for(int it=0;it<8;it+=2){
    int ra = it*256 + tid, rb = (it+1)*256 + tid;
    const float4* Wa = (const float4*)(Wd + (size_t)ra*FFI + j0);
    const float4* Wb = (const float4*)(Wd + (size_t)rb*FFI + j0);
    float4 wa[8], wb[8];
#pragma unroll
    for(int i=0;i<8;i++) wa[i] = Wa[i];
#pragma unroll
    for(int i=0;i<8;i++) wb[i] = Wb[i];
    float aa = 0.f, ab = 0.f;
#pragma unroll
    for(int i=0;i<8;i++){ aa += dot4(wa[i], t8[i]); ab += dot4(wb[i], t8[i]); }
    atomicAdd(&mv[ra], aa);
    atomicAdd(&mv[rb], ab);
  }
}

// ---- plg (redundant per block) + plp, with fused post_ff prologue ----
__global__ __launch_bounds__(256) void plgplp_k(const float* __restrict__ Wpg,
    const float* __restrict__ Wpp, const float* __restrict__ mv,
    const float* __restrict__ hMid, const float* __restrict__ gff,
    const float* __restrict__ pls, float* __restrict__ hFF, float* __restrict__ u){
  __shared__ float hc_s[DIM];
  __shared__ float gb_s[PLD];
  __shared__ float red[4];
  int tid = threadIdx.x, lane = tid & 63, wv = tid >> 6;
  float mvv[8]; float ss1 = 0.f;
#pragma unroll
  for(int i=0;i<8;i++){ mvv[i] = mv[tid + i*256]; ss1 += mvv[i]*mvv[i]; }
  ss1 = blockSum256(ss1, red);
  float r1 = rsqrtf(ss1*(1.f/DIM) + 1e-6f);
#pragma unroll
  for(int i=0;i<8;i++){
    int idx = tid + i*256;
    float hc = hMid[idx] + mvv[i]*r1*gff[idx];
    hc_s[idx] = hc;
    if(blockIdx.x==0) hFF[idx] = hc;
  }
  __syncthreads();
  const float4* hc4 = (const float4*)hc_s;
#pragma unroll 1
  for(int rr=0;rr<64;rr++){
    int r = wv*64 + rr;
    const float4* Wr = (const float4*)(Wpg + (size_t)r*DIM);
    float4 w8[8];
#pragma unroll
    for(int i=0;i<8;i++) w8[i] = Wr[i*64+lane];
    float acc = 0.f;
#pragma unroll
    for(int i=0;i<8;i++) acc += dot4(w8[i], hc4[i*64+lane]);
    acc = waveAllSum(acc);
    if(lane==0) gb_s[r] = gelu_tanh(acc)*pls[r];
  }
  __syncthreads();
  const float4* gb4 = (const float4*)gb_s;
#pragma unroll
  for(int j=0;j<8;j++){
    int r = blockIdx.x*32 + wv*8 + j;
    const float4* Wr = (const float4*)(Wpp + (size_t)r*PLD);
    float acc = dot4(Wr[lane], gb4[lane]);
    acc = waveAllSum(acc);
    if(lane==0) u[r] = acc;
  }
}

// ---- final: out = (hFF + rms(u)*g_pl)*ls ----
__global__ __launch_bounds__(256) void final_k(const float* __restrict__ u,
    const float* __restrict__ hFF, const float* __restrict__ g_pl,
    const float* __restrict__ lsc, float* __restrict__ out){
  __shared__ float red[4];
  int tid = threadIdx.x;
  float uv[8]; float ss1 = 0.f;
#pragma unroll
  for(int i=0;i<8;i++){ uv[i] = u[tid + i*256]; ss1 += uv[i]*uv[i]; }
  ss1 = blockSum256(ss1, red);
  float r1 = rsqrtf(ss1*(1.f/DIM) + 1e-6f);
  float ls = lsc[0];
#pragma unroll
  for(int i=0;i<8;i++){
    int idx = tid + i*256;
    out[idx] = (hFF[idx] + uv[i]*r1*g_pl[idx])*ls;
  }
}

extern "C" void kernel_launch(void* const* d_in, const int* in_sizes, int n_in,
                              void* d_out, int out_size, void* d_ws, size_t ws_size,
                              hipStream_t stream){
  const float* hidden   = (const float*)d_in[0];
  const float* plc      = (const float*)d_in[3];
  const float* cos_s    = (const float*)d_in[4];
  const float* sin_s    = (const float*)d_in[5];
  const float* cos_f    = (const float*)d_in[6];
  const float* sin_f    = (const float*)d_in[7];
  const float* K_in     = (const float*)d_in[8];
  const float* V_in     = (const float*)d_in[9];
  const float* w_q      = (const float*)d_in[10];
  const float* w_k      = (const float*)d_in[11];
  const float* w_v      = (const float*)d_in[12];
  const float* w_o      = (const float*)d_in[13];
  const float* g_in_ln  = (const float*)d_in[14];
  const float* g_q_norm = (const float*)d_in[15];
  const float* g_k_norm = (const float*)d_in[16];
  const float* g_pa_ln  = (const float*)d_in[17];
  const float* g_pf_ln  = (const float*)d_in[18];
  const float* g_ff_ln  = (const float*)d_in[19];
  const float* w_gate   = (const float*)d_in[20];
  const float* w_up     = (const float*)d_in[21];
  const float* w_down   = (const float*)d_in[22];
  const float* w_plg    = (const float*)d_in[23];
  const float* w_plp    = (const float*)d_in[24];
  const float* g_pl_ln  = (const float*)d_in[25];
  const float* l_scal   = (const float*)d_in[26];

  float* out  = (float*)d_out;
  float* outK = out + DIM;
  float* outV = outK + (size_t)NL*NKV*KVL*HD;

  float* ws   = (float*)d_ws;
  float* hRes = ws;
  float* hMid = ws + 2048;
  float* hFF  = ws + 4096;
  float* qkvb = ws + 6144;    // 3072
  float* y    = ws + 9216;    // 2048
  float* mv   = ws + 11264;   // 2048
  float* u    = ws + 13312;   // 2048
  float* pm   = ws + 15360;   // 512
  float* pl   = ws + 15872;   // 512
  float* po   = ws + 16384;   // 8*64*256 = 131072

  (void)hipMemcpyAsync(outK, K_in, (size_t)NL*NKV*KVL*HD*sizeof(float),
                       hipMemcpyDeviceToDevice, stream);
  (void)hipMemcpyAsync(outV, V_in, (size_t)NL*NKV*KVL*HD*sizeof(float),
                       hipMemcpyDeviceToDevice, stream);

  for(int l=0;l<NL;l++){
    const float* cosT = (l==4) ? cos_f : cos_s;
    const float* sinT = (l==4) ? sin_f : sin_s;
    float* Kl = outK + (size_t)l*NKV*KVL*HD;
    float* Vl = outV + (size_t)l*NKV*KVL*HD;
    const float* Ki = K_in + (size_t)l*NKV*KVL*HD;
    const float* Vi = V_in + (size_t)l*NKV*KVL*HD;

    qkv_k<<<768,256,0,stream>>>(
        w_q + (size_t)l*NH*HD*DIM, w_k + (size_t)l*NKV*HD*DIM,
        w_v + (size_t)l*NKV*HD*DIM,
        hFF, u,
        (l>0) ? g_pl_ln + (size_t)(l-1)*DIM : g_pl_ln,
        (l>0) ? l_scal + (l-1) : l_scal,
        g_in_ln + (size_t)l*DIM,
        (l==0) ? hidden : nullptr,
        hRes, qkvb);

    attn_k<<<NKV*NCH+1,256,0,stream>>>(qkvb, g_q_norm + l*HD, g_k_norm + l*HD,
                                       cosT, sinT, Ki, Vi, Kl, Vl, pm, pl, po);

    wo_k<<<128,256,0,stream>>>(w_o + (size_t)l*DIM*NH*HD, pm, pl, po, y, mv);

    gud_k<<<256,256,0,stream>>>(w_gate + (size_t)l*FFI*DIM,
                                w_up + (size_t)l*FFI*DIM,
                                w_down + (size_t)l*DIM*FFI,
                                y, hRes, g_pa_ln + (size_t)l*DIM,
                                g_pf_ln + (size_t)l*DIM, hMid, mv);

    plgplp_k<<<64,256,0,stream>>>(w_plg + (size_t)l*PLD*DIM,
                                  w_plp + (size_t)l*DIM*PLD,
                                  mv, hMid, g_ff_ln + (size_t)l*DIM,
                                  plc + l*PLD, hFF, u);
  }

  final_k<<<1,256,0,stream>>>(u, hFF, g_pl_ln + (size_t)(NL-1)*DIM,
                              l_scal + (NL-1), out);
}

// Round 11
// 871.001 us; speedup vs baseline: 2.7022x; 2.7022x over previous
//
#include <hip/hip_runtime.h>

#define NL   8
#define DIM  2048
#define NH   8
#define NKV  2
#define HD   256
#define KVL  4096
#define FFI  8192
#define PLD  256
#define POS  2047
#define NCH  64
#define CP   32

__device__ __forceinline__ float dot4(float4 a, float4 b){
  return a.x*b.x + a.y*b.y + a.z*b.z + a.w*b.w;
}

__device__ __forceinline__ float waveAllSum(float v){
#pragma unroll
  for(int o=1;o<64;o<<=1) v += __shfl_xor(v,o,64);
  return v;
}

__device__ __forceinline__ float blockSum256(float v, float* red){
  int lane = threadIdx.x & 63, w = threadIdx.x >> 6;
  v = waveAllSum(v);
  __syncthreads();
  if(lane==0) red[w] = v;
  __syncthreads();
  return red[0]+red[1]+red[2]+red[3];
}

__device__ __forceinline__ float gelu_tanh(float v){
  return 0.5f*v*(1.0f + tanhf(0.7978845608028654f*(v + 0.044715f*v*v*v)));
}

__device__ __forceinline__ float4 normRope(const float* __restrict__ raw, int lane,
    const float* __restrict__ gain, const float* __restrict__ cosT,
    const float* __restrict__ sinT, bool doRope){
  float4 v4 = ((const float4*)raw)[lane];
  float ss = waveAllSum(dot4(v4,v4));
  float sc = rsqrtf(ss*(1.f/HD) + 1e-6f);
  float4 n;
  if(gain){
    float4 g4 = ((const float4*)gain)[lane];
    n.x=v4.x*sc*g4.x; n.y=v4.y*sc*g4.y; n.z=v4.z*sc*g4.z; n.w=v4.w*sc*g4.w;
  } else {
    n.x=v4.x*sc; n.y=v4.y*sc; n.z=v4.z*sc; n.w=v4.w*sc;
  }
  if(!doRope) return n;
  float4 np;
  np.x=__shfl_xor(n.x,32,64); np.y=__shfl_xor(n.y,32,64);
  np.z=__shfl_xor(n.z,32,64); np.w=__shfl_xor(n.w,32,64);
  float4 c4 = ((const float4*)cosT)[lane];
  float4 s4 = ((const float4*)sinT)[lane];
  float sg = (lane < 32) ? -1.f : 1.f;
  float4 o;
  o.x = n.x*c4.x + sg*np.x*s4.x;
  o.y = n.y*c4.y + sg*np.y*s4.y;
  o.z = n.z*c4.z + sg*np.z*s4.z;
  o.w = n.w*c4.w + sg*np.w*s4.w;
  return o;
}

// ---- qkv GEMV with fused post_pl (prev layer) / initial prologue ----
__global__ __launch_bounds__(256) void qkv_k(
    const float* __restrict__ Wq, const float* __restrict__ Wk,
    const float* __restrict__ Wv,
    const float* __restrict__ hFF, const float* __restrict__ u,
    const float* __restrict__ g_pl, const float* __restrict__ lsc,
    const float* __restrict__ g_in, const float* __restrict__ hidden,
    float* __restrict__ hRes, float* __restrict__ qkv){
  __shared__ float xs[DIM];
  __shared__ float red[4];
  int tid = threadIdx.x;
  float hv[8];
  if(hidden){
#pragma unroll
    for(int i=0;i<8;i++) hv[i] = hidden[tid + i*256];
  } else {
    float uv[8]; float ss1 = 0.f;
#pragma unroll
    for(int i=0;i<8;i++){ uv[i] = u[tid + i*256]; ss1 += uv[i]*uv[i]; }
    ss1 = blockSum256(ss1, red);
    float r1 = rsqrtf(ss1*(1.f/DIM) + 1e-6f);
    float ls = lsc[0];
#pragma unroll
    for(int i=0;i<8;i++){
      int idx = tid + i*256;
      hv[i] = (hFF[idx] + uv[i]*r1*g_pl[idx])*ls;
    }
  }
  float ss2 = 0.f;
#pragma unroll
  for(int i=0;i<8;i++) ss2 += hv[i]*hv[i];
  ss2 = blockSum256(ss2, red);
  float r2 = rsqrtf(ss2*(1.f/DIM) + 1e-6f);
#pragma unroll
  for(int i=0;i<8;i++){
    int idx = tid + i*256;
    xs[idx] = hv[i]*r2*g_in[idx];
    if(blockIdx.x==0) hRes[idx] = hv[i];
  }
  __syncthreads();
  int lane = tid & 63, wv = tid >> 6;
  int r = blockIdx.x*4 + wv;
  const float* W; int row;
  if(r < 2048){ W = Wq; row = r; }
  else if(r < 2560){ W = Wk; row = r - 2048; }
  else { W = Wv; row = r - 2560; }
  const float4* Wr = (const float4*)(W + (size_t)row*DIM);
  const float4* xs4 = (const float4*)xs;
  float4 w8[8];
#pragma unroll
  for(int i=0;i<8;i++) w8[i] = Wr[i*64+lane];
  float acc = 0.f;
#pragma unroll
  for(int i=0;i<8;i++) acc += dot4(w8[i], xs4[i*64+lane]);
  acc = waveAllSum(acc);
  if(lane==0) qkv[r] = acc;
}

// ---- attention: fused q/k/v norm+rope, flash partials; +1 cache-row writer ----
__global__ __launch_bounds__(256) void attn_k(
    const float* __restrict__ qkvb,
    const float* __restrict__ gq, const float* __restrict__ gk,
    const float* __restrict__ cosT, const float* __restrict__ sinT,
    const float* __restrict__ Ki, const float* __restrict__ Vi,
    float* __restrict__ Kl, float* __restrict__ Vl,
    float* __restrict__ pm, float* __restrict__ pl, float* __restrict__ po){
  int b = blockIdx.x, tid = threadIdx.x, lane = tid & 63, wv = tid >> 6;

  if(b == NKV*NCH){ // cache-row writer
    int kvv = wv >> 1, isV = wv & 1;
    const float* raw = qkvb + (isV ? 2560 : 2048) + kvv*HD;
    float4 o = normRope(raw, lane, isV ? nullptr : gk, cosT, sinT, !isV);
    float* dst = (isV ? Vl : Kl) + ((size_t)kvv*KVL + POS)*HD;
    ((float4*)dst)[lane] = o;
    return;
  }

  int kv = b & 1, c = b >> 1;          // c: 0..63
  __shared__ float q_s[4][HD];
  __shared__ float vf_s[HD];
  __shared__ float s_s[4][CP];
  __shared__ float s_w[4][CP];
  bool fresh = (c == NCH-1);

  { float4 o = normRope(qkvb + (kv*4 + wv)*HD, lane, gq, cosT, sinT, true);
    ((float4*)q_s[wv])[lane] = o; }
  float4 kf4 = {0,0,0,0};
  if(fresh){
    if(wv == 3) kf4 = normRope(qkvb + 2048 + kv*HD, lane, gk, cosT, sinT, true);
    if(wv == 1){
      float4 o = normRope(qkvb + 2560 + kv*HD, lane, nullptr, cosT, sinT, false);
      ((float4*)vf_s)[lane] = o;
    }
  }
  __syncthreads();

  float4 q4[4];
#pragma unroll
  for(int hh=0;hh<4;hh++) q4[hh] = ((const float4*)q_s[hh])[lane];
  const float4* Kp = (const float4*)(Ki + ((size_t)kv*KVL + c*CP)*HD);
#pragma unroll
  for(int j=0;j<8;j++){
    int p = wv*8 + j;
    float4 k4 = (fresh && p==CP-1) ? kf4 : Kp[(size_t)p*64 + lane];
    float d0 = dot4(k4,q4[0]), d1 = dot4(k4,q4[1]);
    float d2 = dot4(k4,q4[2]), d3 = dot4(k4,q4[3]);
    d0 = waveAllSum(d0); d1 = waveAllSum(d1);
    d2 = waveAllSum(d2); d3 = waveAllSum(d3);
    if(lane==0){ s_s[0][p]=d0; s_s[1][p]=d1; s_s[2][p]=d2; s_s[3][p]=d3; }
  }
  __syncthreads();

  if(tid < 128){ // head hh = tid>>5, position pp = tid&31 (32-lane groups)
    int hh = tid >> 5, pp = tid & 31;
    float s = s_s[hh][pp];
    float m = s;
#pragma unroll
    for(int o=1;o<32;o<<=1) m = fmaxf(m, __shfl_xor(m,o,64));
    float e = __expf(s - m);
    float ls = e;
#pragma unroll
    for(int o=1;o<32;o<<=1) ls += __shfl_xor(ls,o,64);
    s_w[hh][pp] = e;
    if(pp==0){ int hg = kv*4 + hh; pm[hg*NCH + c] = m; pl[hg*NCH + c] = ls; }
  }
  __syncthreads();

  int d = tid;
  const float* Vp = Vi + ((size_t)kv*KVL + c*CP)*HD;
  float acc[4] = {0.f,0.f,0.f,0.f};
#pragma unroll 8
  for(int p2=0;p2<CP;p2++){
    float vv = (fresh && p2==CP-1) ? vf_s[d] : Vp[(size_t)p2*HD + d];
#pragma unroll
    for(int hh=0;hh<4;hh++) acc[hh] += s_w[hh][p2]*vv;
  }
#pragma unroll
  for(int hh=0;hh<4;hh++)
    po[((size_t)(kv*4+hh)*NCH + c)*HD + d] = acc[hh];
}

// ---- wo GEMV with fused chunk-combine prologue (256 blocks x 8 rows) ----
__global__ __launch_bounds__(256) void wo_k(const float* __restrict__ Wo,
    const float* __restrict__ pm, const float* __restrict__ pl,
    const float* __restrict__ po, float* __restrict__ y){
  __shared__ float ao_s[DIM];
  __shared__ float se_s[NH][NCH];
  __shared__ float Li[NH];
  int b = blockIdx.x, tid = threadIdx.x, lane = tid & 63, wv = tid >> 6;
  { // combine weights: 8 heads x 32 threads each
    int h = tid >> 5, q2 = tid & 31;
    float m0 = pm[h*NCH + q2], m1 = pm[h*NCH + 32 + q2];
    float l0 = pl[h*NCH + q2], l1 = pl[h*NCH + 32 + q2];
    float m = fmaxf(m0, m1);
#pragma unroll
    for(int o=1;o<32;o<<=1) m = fmaxf(m, __shfl_xor(m,o,64));
    float e0 = __expf(m0-m), e1 = __expf(m1-m);
    se_s[h][q2] = e0; se_s[h][q2+32] = e1;
    float lp = l0*e0 + l1*e1;
#pragma unroll
    for(int o=1;o<32;o<<=1) lp += __shfl_xor(lp,o,64);
    if(q2==0) Li[h] = 1.f/lp;
  }
  __syncthreads();
#pragma unroll 1
  for(int h=0;h<NH;h++){
    float a = 0.f;
#pragma unroll 8
    for(int c=0;c<NCH;c++)
      a += po[((size_t)(h*NCH) + c)*HD + tid]*se_s[h][c];
    ao_s[h*HD + tid] = a*Li[h];
  }
  __syncthreads();
  const float4* xs4 = (const float4*)ao_s;
#pragma unroll
  for(int j=0;j<2;j++){
    int r = b*8 + wv*2 + j;
    const float4* Wr = (const float4*)(Wo + (size_t)r*DIM);
    float4 w8[8];
#pragma unroll
    for(int i=0;i<8;i++) w8[i] = Wr[i*64+lane];
    float acc = 0.f;
#pragma unroll
    for(int i=0;i<8;i++) acc += dot4(w8[i], xs4[i*64+lane]);
    acc = waveAllSum(acc);
    if(lane==0) y[r] = acc;
  }
}

// ---- gate/up GEMV with fused post_attn prologue ----
__global__ __launch_bounds__(256) void gateup_k(const float* __restrict__ Wg,
    const float* __restrict__ Wu, const float* __restrict__ y,
    const float* __restrict__ hRes, const float* __restrict__ g_pa,
    const float* __restrict__ g_pf, float* __restrict__ hMid, float* __restrict__ t){
  __shared__ float xs[DIM];
  __shared__ float red[4];
  int tid = threadIdx.x;
  float yv[8]; float ss1 = 0.f;
#pragma unroll
  for(int i=0;i<8;i++){ yv[i] = y[tid + i*256]; ss1 += yv[i]*yv[i]; }
  ss1 = blockSum256(ss1, red);
  float r1 = rsqrtf(ss1*(1.f/DIM) + 1e-6f);
  float hv[8]; float ss2 = 0.f;
#pragma unroll
  for(int i=0;i<8;i++){
    int idx = tid + i*256;
    hv[i] = hRes[idx] + yv[i]*r1*g_pa[idx];
    ss2 += hv[i]*hv[i];
  }
  ss2 = blockSum256(ss2, red);
  float r2 = rsqrtf(ss2*(1.f/DIM) + 1e-6f);
#pragma unroll
  for(int i=0;i<8;i++){
    int idx = tid + i*256;
    xs[idx] = hv[i]*r2*g_pf[idx];
    if(blockIdx.x==0) hMid[idx] = hv[i];
  }
  __syncthreads();
  int lane = tid & 63, wv = tid >> 6;
  int j = blockIdx.x*4 + wv;
  const float4* Gr = (const float4*)(Wg + (size_t)j*DIM);
  const float4* Ur = (const float4*)(Wu + (size_t)j*DIM);
  const float4* xs4 = (const float4*)xs;
  float4 g8[8], u8[8];
#pragma unroll
  for(int i=0;i<8;i++) g8[i] = Gr[i*64+lane];
#pragma unroll
  for(int i=0;i<8;i++) u8[i] = Ur[i*64+lane];
  float ag = 0.f, au = 0.f;
#pragma unroll
  for(int i=0;i<8;i++){
    float4 bv = xs4[i*64+lane];
    ag += dot4(g8[i], bv);
    au += dot4(u8[i], bv);
  }
  ag = waveAllSum(ag);
  au = waveAllSum(au);
  if(lane==0) t[j] = gelu_tanh(ag)*au;
}

// ---- down GEMV: 1 row per block, 4-wave column split ----
__global__ __launch_bounds__(256) void down_k(const float* __restrict__ Wd,
    const float* __restrict__ t, float* __restrict__ mv){
  __shared__ float red[4];
  int tid = threadIdx.x, lane = tid & 63, wv = tid >> 6;
  int r = blockIdx.x;
  const float4* Wr = (const float4*)(Wd + (size_t)r*FFI) + wv*512;
  const float4* tp = (const float4*)t + wv*512;
  float4 w8[8], t8[8];
#pragma unroll
  for(int i=0;i<8;i++) w8[i] = Wr[i*64+lane];
#pragma unroll
  for(int i=0;i<8;i++) t8[i] = tp[i*64+lane];
  float acc = 0.f;
#pragma unroll
  for(int i=0;i<8;i++) acc += dot4(w8[i], t8[i]);
  acc = waveAllSum(acc);
  if(lane==0) red[wv] = acc;
  __syncthreads();
  if(tid==0) mv[r] = red[0]+red[1]+red[2]+red[3];
}

// ---- plg GEMV with fused post_ff prologue ----
__global__ __launch_bounds__(256) void plg_k(const float* __restrict__ W,
    const float* __restrict__ mv, const float* __restrict__ hMid,
    const float* __restrict__ g_ff, const float* __restrict__ pls,
    float* __restrict__ hFFout, float* __restrict__ gb){
  __shared__ float xs[DIM];
  __shared__ float red[4];
  int tid = threadIdx.x;
  float mvv[8]; float ss1 = 0.f;
#pragma unroll
  for(int i=0;i<8;i++){ mvv[i] = mv[tid + i*256]; ss1 += mvv[i]*mvv[i]; }
  ss1 = blockSum256(ss1, red);
  float r1 = rsqrtf(ss1*(1.f/DIM) + 1e-6f);
#pragma unroll
  for(int i=0;i<8;i++){
    int idx = tid + i*256;
    float hc = hMid[idx] + mvv[i]*r1*g_ff[idx];
    xs[idx] = hc;
    if(blockIdx.x==0) hFFout[idx] = hc;
  }
  __syncthreads();
  int lane = tid & 63, wv = tid >> 6;
  int r = blockIdx.x*4 + wv;
  const float4* Wr = (const float4*)(W + (size_t)r*DIM);
  const float4* xs4 = (const float4*)xs;
  float4 w8[8];
#pragma unroll
  for(int i=0;i<8;i++) w8[i] = Wr[i*64+lane];
  float acc = 0.f;
#pragma unroll
  for(int i=0;i<8;i++) acc += dot4(w8[i], xs4[i*64+lane]);
  acc = waveAllSum(acc);
  if(lane==0) gb[r] = gelu_tanh(acc)*pls[r];
}

// ---- plp GEMV (256-col) ----
__global__ __launch_bounds__(256) void plp_k(const float* __restrict__ W,
    const float* __restrict__ gb, float* __restrict__ u){
  __shared__ float xs[PLD];
  if(threadIdx.x < PLD/4)
    ((float4*)xs)[threadIdx.x] = ((const float4*)gb)[threadIdx.x];
  __syncthreads();
  int lane = threadIdx.x & 63, wv = threadIdx.x >> 6;
  int r = blockIdx.x*4 + wv;
  const float4* Wr = (const float4*)(W + (size_t)r*PLD);
  float acc = dot4(Wr[lane], ((const float4*)xs)[lane]);
  acc = waveAllSum(acc);
  if(lane==0) u[r] = acc;
}

// ---- final: out = (hFF + rms(u)*g_pl)*ls ----
__global__ __launch_bounds__(256) void final_k(const float* __restrict__ u,
    const float* __restrict__ hFF, const float* __restrict__ g_pl,
    const float* __restrict__ lsc, float* __restrict__ out){
  __shared__ float red[4];
  int tid = threadIdx.x;
  float uv[8]; float ss1 = 0.f;
#pragma unroll
  for(int i=0;i<8;i++){ uv[i] = u[tid + i*256]; ss1 += uv[i]*uv[i]; }
  ss1 = blockSum256(ss1, red);
  float r1 = rsqrtf(ss1*(1.f/DIM) + 1e-6f);
  float ls = lsc[0];
#pragma unroll
  for(int i=0;i<8;i++){
    int idx = tid + i*256;
    out[idx] = (hFF[idx] + uv[i]*r1*g_pl[idx])*ls;
  }
}

extern "C" void kernel_launch(void* const* d_in, const int* in_sizes, int n_in,
                              void* d_out, int out_size, void* d_ws, size_t ws_size,
                              hipStream_t stream){
  const float* hidden   = (const float*)d_in[0];
  const float* plc      = (const float*)d_in[3];
  const float* cos_s    = (const float*)d_in[4];
  const float* sin_s    = (const float*)d_in[5];
  const float* cos_f    = (const float*)d_in[6];
  const float* sin_f    = (const float*)d_in[7];
  const float* K_in     = (const float*)d_in[8];
  const float* V_in     = (const float*)d_in[9];
  const float* w_q      = (const float*)d_in[10];
  const float* w_k      = (const float*)d_in[11];
  const float* w_v      = (const float*)d_in[12];
  const float* w_o      = (const float*)d_in[13];
  const float* g_in_ln  = (const float*)d_in[14];
  const float* g_q_norm = (const float*)d_in[15];
  const float* g_k_norm = (const float*)d_in[16];
  const float* g_pa_ln  = (const float*)d_in[17];
  const float* g_pf_ln  = (const float*)d_in[18];
  const float* g_ff_ln  = (const float*)d_in[19];
  const float* w_gate   = (const float*)d_in[20];
  const float* w_up     = (const float*)d_in[21];
  const float* w_down   = (const float*)d_in[22];
  const float* w_plg    = (const float*)d_in[23];
  const float* w_plp    = (const float*)d_in[24];
  const float* g_pl_ln  = (const float*)d_in[25];
  const float* l_scal   = (const float*)d_in[26];

  float* out  = (float*)d_out;
  float* outK = out + DIM;
  float* outV = outK + (size_t)NL*NKV*KVL*HD;

  float* ws   = (float*)d_ws;
  float* hRes = ws;
  float* hMid = ws + 2048;
  float* hFF  = ws + 4096;
  float* qkvb = ws + 6144;    // 3072
  float* y    = ws + 9216;    // 2048
  float* t    = ws + 11264;   // 8192
  float* mv   = ws + 19456;   // 2048
  float* gb   = ws + 21504;   // 256
  float* u    = ws + 21760;   // 2048
  float* pm   = ws + 23808;   // 512
  float* pl   = ws + 24320;   // 512
  float* po   = ws + 24832;   // 8*64*256 = 131072

  (void)hipMemcpyAsync(outK, K_in, (size_t)NL*NKV*KVL*HD*sizeof(float),
                       hipMemcpyDeviceToDevice, stream);
  (void)hipMemcpyAsync(outV, V_in, (size_t)NL*NKV*KVL*HD*sizeof(float),
                       hipMemcpyDeviceToDevice, stream);

  for(int l=0;l<NL;l++){
    const float* cosT = (l==4) ? cos_f : cos_s;
    const float* sinT = (l==4) ? sin_f : sin_s;
    float* Kl = outK + (size_t)l*NKV*KVL*HD;
    float* Vl = outV + (size_t)l*NKV*KVL*HD;
    const float* Ki = K_in + (size_t)l*NKV*KVL*HD;
    const float* Vi = V_in + (size_t)l*NKV*KVL*HD;

    qkv_k<<<768,256,0,stream>>>(
        w_q + (size_t)l*NH*HD*DIM, w_k + (size_t)l*NKV*HD*DIM,
        w_v + (size_t)l*NKV*HD*DIM,
        hFF, u,
        (l>0) ? g_pl_ln + (size_t)(l-1)*DIM : g_pl_ln,
        (l>0) ? l_scal + (l-1) : l_scal,
        g_in_ln + (size_t)l*DIM,
        (l==0) ? hidden : nullptr,
        hRes, qkvb);

    attn_k<<<NKV*NCH+1,256,0,stream>>>(qkvb, g_q_norm + l*HD, g_k_norm + l*HD,
                                       cosT, sinT, Ki, Vi, Kl, Vl, pm, pl, po);

    wo_k<<<256,256,0,stream>>>(w_o + (size_t)l*DIM*NH*HD, pm, pl, po, y);

    gateup_k<<<FFI/4,256,0,stream>>>(w_gate + (size_t)l*FFI*DIM,
                                     w_up + (size_t)l*FFI*DIM,
                                     y, hRes, g_pa_ln + (size_t)l*DIM,
                                     g_pf_ln + (size_t)l*DIM, hMid, t);

    down_k<<<DIM,256,0,stream>>>(w_down + (size_t)l*DIM*FFI, t, mv);

    plg_k<<<PLD/4,256,0,stream>>>(w_plg + (size_t)l*PLD*DIM, mv, hMid,
                                  g_ff_ln + (size_t)l*DIM, plc + l*PLD, hFF, gb);

    plp_k<<<512,256,0,stream>>>(w_plp + (size_t)l*DIM*PLD, gb, u);
  }

  final_k<<<1,256,0,stream>>>(u, hFF, g_pl_ln + (size_t)(NL-1)*DIM,
                              l_scal + (NL-1), out);
}

// Round 12
// 782.118 us; speedup vs baseline: 3.0093x; 1.1136x over previous
//
#include <hip/hip_runtime.h>

#define NL   8
#define DIM  2048
#define NH   8
#define NKV  2
#define HD   256
#define KVL  4096
#define FFI  8192
#define PLD  256
#define POS  2047
#define NCH  128   // attention chunks over live positions
#define CP   16

typedef float vfloat4 __attribute__((ext_vector_type(4)));

__device__ __forceinline__ float dot4(float4 a, float4 b){
  return a.x*b.x + a.y*b.y + a.z*b.z + a.w*b.w;
}

__device__ __forceinline__ float4 ntld4(const float4* p){
  vfloat4 v = __builtin_nontemporal_load((const vfloat4*)p);
  float4 r; r.x=v.x; r.y=v.y; r.z=v.z; r.w=v.w; return r;
}
__device__ __forceinline__ void ntst4(float4* p, float4 v){
  vfloat4 t; t.x=v.x; t.y=v.y; t.z=v.z; t.w=v.w;
  __builtin_nontemporal_store(t, (vfloat4*)p);
}

__device__ __forceinline__ float waveAllSum(float v){
#pragma unroll
  for(int o=1;o<64;o<<=1) v += __shfl_xor(v,o,64);
  return v;
}

__device__ __forceinline__ float blockSum256(float v, float* red){
  int lane = threadIdx.x & 63, w = threadIdx.x >> 6;
  v = waveAllSum(v);
  __syncthreads();
  if(lane==0) red[w] = v;
  __syncthreads();
  return red[0]+red[1]+red[2]+red[3];
}

__device__ __forceinline__ float gelu_tanh(float v){
  return 0.5f*v*(1.0f + tanhf(0.7978845608028654f*(v + 0.044715f*v*v*v)));
}

__device__ __forceinline__ float4 normRope(const float* __restrict__ raw, int lane,
    const float* __restrict__ gain, const float* __restrict__ cosT,
    const float* __restrict__ sinT, bool doRope){
  float4 v4 = ((const float4*)raw)[lane];
  float ss = waveAllSum(dot4(v4,v4));
  float sc = rsqrtf(ss*(1.f/HD) + 1e-6f);
  float4 n;
  if(gain){
    float4 g4 = ((const float4*)gain)[lane];
    n.x=v4.x*sc*g4.x; n.y=v4.y*sc*g4.y; n.z=v4.z*sc*g4.z; n.w=v4.w*sc*g4.w;
  } else {
    n.x=v4.x*sc; n.y=v4.y*sc; n.z=v4.z*sc; n.w=v4.w*sc;
  }
  if(!doRope) return n;
  float4 np;
  np.x=__shfl_xor(n.x,32,64); np.y=__shfl_xor(n.y,32,64);
  np.z=__shfl_xor(n.z,32,64); np.w=__shfl_xor(n.w,32,64);
  float4 c4 = ((const float4*)cosT)[lane];
  float4 s4 = ((const float4*)sinT)[lane];
  float sg = (lane < 32) ? -1.f : 1.f;
  float4 o;
  o.x = n.x*c4.x + sg*np.x*s4.x;
  o.y = n.y*c4.y + sg*np.y*s4.y;
  o.z = n.z*c4.z + sg*np.z*s4.z;
  o.w = n.w*c4.w + sg*np.w*s4.w;
  return o;
}

// ---- qkv GEMV with fused post_pl (prev layer) / initial prologue ----
__global__ __launch_bounds__(256) void qkv_k(
    const float* __restrict__ Wq, const float* __restrict__ Wk,
    const float* __restrict__ Wv,
    const float* __restrict__ hFF, const float* __restrict__ u,
    const float* __restrict__ g_pl, const float* __restrict__ lsc,
    const float* __restrict__ g_in, const float* __restrict__ hidden,
    float* __restrict__ hRes, float* __restrict__ qkv){
  __shared__ float xs[DIM];
  __shared__ float red[4];
  int tid = threadIdx.x;
  float hv[8];
  if(hidden){
#pragma unroll
    for(int i=0;i<8;i++) hv[i] = hidden[tid + i*256];
  } else {
    float uv[8]; float ss1 = 0.f;
#pragma unroll
    for(int i=0;i<8;i++){ uv[i] = u[tid + i*256]; ss1 += uv[i]*uv[i]; }
    ss1 = blockSum256(ss1, red);
    float r1 = rsqrtf(ss1*(1.f/DIM) + 1e-6f);
    float ls = lsc[0];
#pragma unroll
    for(int i=0;i<8;i++){
      int idx = tid + i*256;
      hv[i] = (hFF[idx] + uv[i]*r1*g_pl[idx])*ls;
    }
  }
  float ss2 = 0.f;
#pragma unroll
  for(int i=0;i<8;i++) ss2 += hv[i]*hv[i];
  ss2 = blockSum256(ss2, red);
  float r2 = rsqrtf(ss2*(1.f/DIM) + 1e-6f);
#pragma unroll
  for(int i=0;i<8;i++){
    int idx = tid + i*256;
    xs[idx] = hv[i]*r2*g_in[idx];
    if(blockIdx.x==0) hRes[idx] = hv[i];
  }
  __syncthreads();
  int lane = tid & 63, wv = tid >> 6;
  int r = blockIdx.x*4 + wv;
  const float* W; int row;
  if(r < 2048){ W = Wq; row = r; }
  else if(r < 2560){ W = Wk; row = r - 2048; }
  else { W = Wv; row = r - 2560; }
  const float4* Wr = (const float4*)(W + (size_t)row*DIM);
  const float4* xs4 = (const float4*)xs;
  float4 w8[8];
#pragma unroll
  for(int i=0;i<8;i++) w8[i] = Wr[i*64+lane];
  float acc = 0.f;
#pragma unroll
  for(int i=0;i<8;i++) acc += dot4(w8[i], xs4[i*64+lane]);
  acc = waveAllSum(acc);
  if(lane==0) qkv[r] = acc;
}

// ---- attention with fused KV-cache copy ----
// blocks [0,256): (kv,chunk) flash partials, reading K_in/V_in and copying
//                 those rows into the output caches (nontemporal)
// block 256: POS-row writer (fresh normalized k/v)
// blocks [257, 257+256): copy masked half (positions 2048..4095)
__global__ __launch_bounds__(256) void attn_k(
    const float* __restrict__ qkvb,
    const float* __restrict__ gq, const float* __restrict__ gk,
    const float* __restrict__ cosT, const float* __restrict__ sinT,
    const float* __restrict__ Ki, const float* __restrict__ Vi,
    float* __restrict__ Kl, float* __restrict__ Vl,
    float* __restrict__ pm, float* __restrict__ pl, float* __restrict__ po){
  int b = blockIdx.x, tid = threadIdx.x, lane = tid & 63, wv = tid >> 6;

  if(b == NKV*NCH){ // POS-row writer
    int kvv = wv >> 1, isV = wv & 1;
    const float* raw = qkvb + (isV ? 2560 : 2048) + kvv*HD;
    float4 o = normRope(raw, lane, isV ? nullptr : gk, cosT, sinT, !isV);
    float* dst = (isV ? Vl : Kl) + ((size_t)kvv*KVL + POS)*HD;
    ((float4*)dst)[lane] = o;
    return;
  }
  if(b > NKV*NCH){ // masked-half copy filler: rows 2048..4095 x {K,V} x {kv}
    int b2 = b - (NKV*NCH+1);           // 0..255
#pragma unroll
    for(int i=0;i<8;i++){
      int ri = b2*32 + wv*8 + i;        // 0..8191
      int combo = ri >> 11;             // 0..3: Kkv0,Kkv1,Vkv0,Vkv1
      int pos = 2048 + (ri & 2047);
      size_t off = ((size_t)(combo&1)*KVL + pos)*HD;
      const float4* s = (const float4*)(((combo>>1) ? Vi : Ki) + off);
      float4* d = (float4*)(((combo>>1) ? Vl : Kl) + off);
      ntst4(d + lane, ntld4(s + lane));
    }
    return;
  }

  int kv = b & 1, c = b >> 1;          // c: 0..127
  __shared__ float q_s[4][HD];
  __shared__ float vf_s[HD];
  __shared__ float s_s[4][CP];
  __shared__ float s_w[4][CP];
  bool fresh = (c == NCH-1);

  { float4 o = normRope(qkvb + (kv*4 + wv)*HD, lane, gq, cosT, sinT, true);
    ((float4*)q_s[wv])[lane] = o; }
  float4 kf4 = {0,0,0,0};
  if(fresh){
    if(wv == 3) kf4 = normRope(qkvb + 2048 + kv*HD, lane, gk, cosT, sinT, true);
    if(wv == 1){
      float4 o = normRope(qkvb + 2560 + kv*HD, lane, nullptr, cosT, sinT, false);
      ((float4*)vf_s)[lane] = o;
    }
  }
  __syncthreads();

  float4 q4[4];
#pragma unroll
  for(int hh=0;hh<4;hh++) q4[hh] = ((const float4*)q_s[hh])[lane];
  const float4* Kp = (const float4*)(Ki + ((size_t)kv*KVL + c*CP)*HD);
  float4* Kd = (float4*)(Kl + ((size_t)kv*KVL + c*CP)*HD);
#pragma unroll
  for(int j=0;j<4;j++){
    int p = wv*4 + j;
    bool isFreshRow = (fresh && p==CP-1);
    float4 k4;
    if(isFreshRow) k4 = kf4;
    else {
      k4 = Kp[(size_t)p*64 + lane];
      ntst4(Kd + (size_t)p*64 + lane, k4);   // fused copy
    }
    float d0 = dot4(k4,q4[0]), d1 = dot4(k4,q4[1]);
    float d2 = dot4(k4,q4[2]), d3 = dot4(k4,q4[3]);
    d0 = waveAllSum(d0); d1 = waveAllSum(d1);
    d2 = waveAllSum(d2); d3 = waveAllSum(d3);
    if(lane==0){ s_s[0][p]=d0; s_s[1][p]=d1; s_s[2][p]=d2; s_s[3][p]=d3; }
  }
  __syncthreads();

  if(tid < 64){ // per-head softmax over 16 positions (16-lane groups)
    int hh = tid >> 4, pp = tid & 15;
    float s = s_s[hh][pp];
    float m = s;
#pragma unroll
    for(int o=1;o<16;o<<=1) m = fmaxf(m, __shfl_xor(m,o,64));
    float e = __expf(s - m);
    float ls = e;
#pragma unroll
    for(int o=1;o<16;o<<=1) ls += __shfl_xor(ls,o,64);
    s_w[hh][pp] = e;
    if(pp==0){ int hg = kv*4 + hh; pm[hg*NCH + c] = m; pl[hg*NCH + c] = ls; }
  }
  __syncthreads();

  int d = tid;
  const float* Vp = Vi + ((size_t)kv*KVL + c*CP)*HD;
  float* Vd = Vl + ((size_t)kv*KVL + c*CP)*HD;
  float vv[CP];
#pragma unroll
  for(int p2=0;p2<CP;p2++){
    bool isFreshRow = (fresh && p2==CP-1);
    if(isFreshRow) vv[p2] = vf_s[d];
    else {
      vv[p2] = Vp[(size_t)p2*HD + d];
      Vd[(size_t)p2*HD + d] = vv[p2];        // fused copy (coalesced)
    }
  }
  float acc[4] = {0.f,0.f,0.f,0.f};
#pragma unroll
  for(int p2=0;p2<CP;p2++){
#pragma unroll
    for(int hh=0;hh<4;hh++) acc[hh] += s_w[hh][p2]*vv[p2];
  }
#pragma unroll
  for(int hh=0;hh<4;hh++)
    po[((size_t)(kv*4+hh)*NCH + c)*HD + d] = acc[hh];
}

// ---- combine chunk partials -> ao ----
__global__ __launch_bounds__(256) void attn_c(const float* __restrict__ pm,
    const float* __restrict__ pl, const float* __restrict__ po, float* __restrict__ ao){
  int h = blockIdx.x, tid = threadIdx.x;
  __shared__ float sm[NCH], sl[NCH], se[NCH];
  if(tid < NCH){ sm[tid] = pm[h*NCH+tid]; sl[tid] = pl[h*NCH+tid]; }
  __syncthreads();
  float M = -1e30f;
  for(int c=0;c<NCH;c++) M = fmaxf(M, sm[c]);
  if(tid < NCH) se[tid] = __expf(sm[tid]-M);
  __syncthreads();
  float Lh = 0.f;
  for(int c=0;c<NCH;c++) Lh += sl[c]*se[c];
  float a0=0.f, a1=0.f, a2=0.f, a3=0.f;
#pragma unroll 1
  for(int c=0;c<NCH;c+=4){
    a0 += po[((size_t)h*NCH + c  )*HD + tid]*se[c];
    a1 += po[((size_t)h*NCH + c+1)*HD + tid]*se[c+1];
    a2 += po[((size_t)h*NCH + c+2)*HD + tid]*se[c+2];
    a3 += po[((size_t)h*NCH + c+3)*HD + tid]*se[c+3];
  }
  ao[h*HD + tid] = (a0+a1+a2+a3) / Lh;
}

// ---- generic GEMV: y[r] = W[r,:] . x  (batched loads) ----
template<int C>
__global__ __launch_bounds__(256) void gemv_k(const float* __restrict__ W,
    const float* __restrict__ x, float* __restrict__ y){
  __shared__ float xs[C];
  for(int i=threadIdx.x; i<C/4; i+=256)
    ((float4*)xs)[i] = ((const float4*)x)[i];
  __syncthreads();
  int lane = threadIdx.x & 63, wv = threadIdx.x >> 6;
  int r = blockIdx.x*4 + wv;
  const float4* Wr = (const float4*)(W + (size_t)r*C);
  const float4* xs4 = (const float4*)xs;
  float acc = 0.f;
#pragma unroll
  for(int ii=0;ii<C/2048;ii++){
    float4 w8[8];
#pragma unroll
    for(int i=0;i<8 && ii*8+i < C/256;i++) w8[i] = Wr[(ii*8+i)*64+lane];
#pragma unroll
    for(int i=0;i<8 && ii*8+i < C/256;i++) acc += dot4(w8[i], xs4[(ii*8+i)*64+lane]);
  }
  if(C < 2048){
    float4 w1 = Wr[lane];
    acc = dot4(w1, xs4[lane]);
  }
  acc = waveAllSum(acc);
  if(lane==0) y[r] = acc;
}

// ---- gate/up GEMV with fused post_attn prologue ----
__global__ __launch_bounds__(256) void gateup_k(const float* __restrict__ Wg,
    const float* __restrict__ Wu, const float* __restrict__ y,
    const float* __restrict__ hRes, const float* __restrict__ g_pa,
    const float* __restrict__ g_pf, float* __restrict__ hMid, float* __restrict__ t){
  __shared__ float xs[DIM];
  __shared__ float red[4];
  int tid = threadIdx.x;
  float yv[8]; float ss1 = 0.f;
#pragma unroll
  for(int i=0;i<8;i++){ yv[i] = y[tid + i*256]; ss1 += yv[i]*yv[i]; }
  ss1 = blockSum256(ss1, red);
  float r1 = rsqrtf(ss1*(1.f/DIM) + 1e-6f);
  float hv[8]; float ss2 = 0.f;
#pragma unroll
  for(int i=0;i<8;i++){
    int idx = tid + i*256;
    hv[i] = hRes[idx] + yv[i]*r1*g_pa[idx];
    ss2 += hv[i]*hv[i];
  }
  ss2 = blockSum256(ss2, red);
  float r2 = rsqrtf(ss2*(1.f/DIM) + 1e-6f);
#pragma unroll
  for(int i=0;i<8;i++){
    int idx = tid + i*256;
    xs[idx] = hv[i]*r2*g_pf[idx];
    if(blockIdx.x==0) hMid[idx] = hv[i];
  }
  __syncthreads();
  int lane = tid & 63, wv = tid >> 6;
  int j = blockIdx.x*4 + wv;
  const float4* Gr = (const float4*)(Wg + (size_t)j*DIM);
  const float4* Ur = (const float4*)(Wu + (size_t)j*DIM);
  const float4* xs4 = (const float4*)xs;
  float4 g8[8], u8[8];
#pragma unroll
  for(int i=0;i<8;i++) g8[i] = Gr[i*64+lane];
#pragma unroll
  for(int i=0;i<8;i++) u8[i] = Ur[i*64+lane];
  float ag = 0.f, au = 0.f;
#pragma unroll
  for(int i=0;i<8;i++){
    float4 bv = xs4[i*64+lane];
    ag += dot4(g8[i], bv);
    au += dot4(u8[i], bv);
  }
  ag = waveAllSum(ag);
  au = waveAllSum(au);
  if(lane==0) t[j] = gelu_tanh(ag)*au;
}

// ---- down GEMV: 1 row per block, 4-wave column split ----
__global__ __launch_bounds__(256) void down_k(const float* __restrict__ Wd,
    const float* __restrict__ t, float* __restrict__ mv){
  __shared__ float red[4];
  int tid = threadIdx.x, lane = tid & 63, wv = tid >> 6;
  int r = blockIdx.x;
  const float4* Wr = (const float4*)(Wd + (size_t)r*FFI) + wv*512;
  const float4* tp = (const float4*)t + wv*512;
  float4 w8[8], t8[8];
#pragma unroll
  for(int i=0;i<8;i++) w8[i] = Wr[i*64+lane];
#pragma unroll
  for(int i=0;i<8;i++) t8[i] = tp[i*64+lane];
  float acc = 0.f;
#pragma unroll
  for(int i=0;i<8;i++) acc += dot4(w8[i], t8[i]);
  acc = waveAllSum(acc);
  if(lane==0) red[wv] = acc;
  __syncthreads();
  if(tid==0) mv[r] = red[0]+red[1]+red[2]+red[3];
}

// ---- plg GEMV with fused post_ff prologue ----
__global__ __launch_bounds__(256) void plg_k(const float* __restrict__ W,
    const float* __restrict__ mv, const float* __restrict__ hMid,
    const float* __restrict__ g_ff, const float* __restrict__ pls,
    float* __restrict__ hFFout, float* __restrict__ gb){
  __shared__ float xs[DIM];
  __shared__ float red[4];
  int tid = threadIdx.x;
  float mvv[8]; float ss1 = 0.f;
#pragma unroll
  for(int i=0;i<8;i++){ mvv[i] = mv[tid + i*256]; ss1 += mvv[i]*mvv[i]; }
  ss1 = blockSum256(ss1, red);
  float r1 = rsqrtf(ss1*(1.f/DIM) + 1e-6f);
#pragma unroll
  for(int i=0;i<8;i++){
    int idx = tid + i*256;
    float hc = hMid[idx] + mvv[i]*r1*g_ff[idx];
    xs[idx] = hc;
    if(blockIdx.x==0) hFFout[idx] = hc;
  }
  __syncthreads();
  int lane = tid & 63, wv = tid >> 6;
  int r = blockIdx.x*4 + wv;
  const float4* Wr = (const float4*)(W + (size_t)r*DIM);
  const float4* xs4 = (const float4*)xs;
  float4 w8[8];
#pragma unroll
  for(int i=0;i<8;i++) w8[i] = Wr[i*64+lane];
  float acc = 0.f;
#pragma unroll
  for(int i=0;i<8;i++) acc += dot4(w8[i], xs4[i*64+lane]);
  acc = waveAllSum(acc);
  if(lane==0) gb[r] = gelu_tanh(acc)*pls[r];
}

// ---- final: out = (hFF + rms(u)*g_pl)*ls ----
__global__ __launch_bounds__(256) void final_k(const float* __restrict__ u,
    const float* __restrict__ hFF, const float* __restrict__ g_pl,
    const float* __restrict__ lsc, float* __restrict__ out){
  __shared__ float red[4];
  int tid = threadIdx.x;
  float uv[8]; float ss1 = 0.f;
#pragma unroll
  for(int i=0;i<8;i++){ uv[i] = u[tid + i*256]; ss1 += uv[i]*uv[i]; }
  ss1 = blockSum256(ss1, red);
  float r1 = rsqrtf(ss1*(1.f/DIM) + 1e-6f);
  float ls = lsc[0];
#pragma unroll
  for(int i=0;i<8;i++){
    int idx = tid + i*256;
    out[idx] = (hFF[idx] + uv[i]*r1*g_pl[idx])*ls;
  }
}

extern "C" void kernel_launch(void* const* d_in, const int* in_sizes, int n_in,
                              void* d_out, int out_size, void* d_ws, size_t ws_size,
                              hipStream_t stream){
  const float* hidden   = (const float*)d_in[0];
  const float* plc      = (const float*)d_in[3];
  const float* cos_s    = (const float*)d_in[4];
  const float* sin_s    = (const float*)d_in[5];
  const float* cos_f    = (const float*)d_in[6];
  const float* sin_f    = (const float*)d_in[7];
  const float* K_in     = (const float*)d_in[8];
  const float* V_in     = (const float*)d_in[9];
  const float* w_q      = (const float*)d_in[10];
  const float* w_k      = (const float*)d_in[11];
  const float* w_v      = (const float*)d_in[12];
  const float* w_o      = (const float*)d_in[13];
  const float* g_in_ln  = (const float*)d_in[14];
  const float* g_q_norm = (const float*)d_in[15];
  const float* g_k_norm = (const float*)d_in[16];
  const float* g_pa_ln  = (const float*)d_in[17];
  const float* g_pf_ln  = (const float*)d_in[18];
  const float* g_ff_ln  = (const float*)d_in[19];
  const float* w_gate   = (const float*)d_in[20];
  const float* w_up     = (const float*)d_in[21];
  const float* w_down   = (const float*)d_in[22];
  const float* w_plg    = (const float*)d_in[23];
  const float* w_plp    = (const float*)d_in[24];
  const float* g_pl_ln  = (const float*)d_in[25];
  const float* l_scal   = (const float*)d_in[26];

  float* out  = (float*)d_out;
  float* outK = out + DIM;
  float* outV = outK + (size_t)NL*NKV*KVL*HD;

  float* ws   = (float*)d_ws;
  float* hRes = ws;
  float* hMid = ws + 2048;
  float* hFF  = ws + 4096;
  float* qkvb = ws + 6144;    // 3072
  float* y    = ws + 9216;    // 2048
  float* t    = ws + 11264;   // 8192
  float* mv   = ws + 19456;   // 2048
  float* gb   = ws + 21504;   // 256
  float* u    = ws + 21760;   // 2048
  float* pm   = ws + 23808;   // 1024
  float* pl   = ws + 24832;   // 1024
  float* po   = ws + 25856;   // 8*128*256 = 262144
  float* ao   = ws + 288000;  // 2048

  for(int l=0;l<NL;l++){
    const float* cosT = (l==4) ? cos_f : cos_s;
    const float* sinT = (l==4) ? sin_f : sin_s;
    float* Kl = outK + (size_t)l*NKV*KVL*HD;
    float* Vl = outV + (size_t)l*NKV*KVL*HD;
    const float* Ki = K_in + (size_t)l*NKV*KVL*HD;
    const float* Vi = V_in + (size_t)l*NKV*KVL*HD;

    qkv_k<<<768,256,0,stream>>>(
        w_q + (size_t)l*NH*HD*DIM, w_k + (size_t)l*NKV*HD*DIM,
        w_v + (size_t)l*NKV*HD*DIM,
        hFF, u,
        (l>0) ? g_pl_ln + (size_t)(l-1)*DIM : g_pl_ln,
        (l>0) ? l_scal + (l-1) : l_scal,
        g_in_ln + (size_t)l*DIM,
        (l==0) ? hidden : nullptr,
        hRes, qkvb);

    attn_k<<<NKV*NCH+1+256,256,0,stream>>>(qkvb, g_q_norm + l*HD,
                                           g_k_norm + l*HD, cosT, sinT,
                                           Ki, Vi, Kl, Vl, pm, pl, po);

    attn_c<<<NH,256,0,stream>>>(pm, pl, po, ao);

    gemv_k<DIM><<<512,256,0,stream>>>(w_o + (size_t)l*DIM*NH*HD, ao, y);

    gateup_k<<<FFI/4,256,0,stream>>>(w_gate + (size_t)l*FFI*DIM,
                                     w_up + (size_t)l*FFI*DIM,
                                     y, hRes, g_pa_ln + (size_t)l*DIM,
                                     g_pf_ln + (size_t)l*DIM, hMid, t);

    down_k<<<DIM,256,0,stream>>>(w_down + (size_t)l*DIM*FFI, t, mv);

    plg_k<<<PLD/4,256,0,stream>>>(w_plg + (size_t)l*PLD*DIM, mv, hMid,
                                  g_ff_ln + (size_t)l*DIM, plc + l*PLD, hFF, gb);

    gemv_k<PLD><<<512,256,0,stream>>>(w_plp + (size_t)l*DIM*PLD, gb, u);
  }

  final_k<<<1,256,0,stream>>>(u, hFF, g_pl_ln + (size_t)(NL-1)*DIM,
                              l_scal + (NL-1), out);
}